// Round 9
// baseline (358.787 us; speedup 1.0000x reference)
//
#include <hip/hip_runtime.h>
#include <math.h>

// Problem constants (from reference setup): T=4, B=64, N=1024, P=63, D=128
#define T_STEPS 4
#define R_ROWS  65536              // B*N rows per timestep
#define M_ROWS  262144             // T*B*N total rows
#define P_DIM   63
#define D_DIM   128
#define PP      64                 // padded P (col 63 = virtual ones column in K1)

#define TILES_TOTAL (M_ROWS / 64)  // 4096 tiles of 64 rows
#define G_CHUNKS 8                 // reduce output copies consumed by stats

typedef float v4f __attribute__((ext_vector_type(4)));

// ---------------------------------------------------------------------------
// K1: per-block partial Gram  P_b = xa_b^T xa_b  (xa = x + ones column).
// Round-9 redesign: 64-thread (single-wave) blocks, 8x8 per-thread G-tile
// (1.0 B LDS per lane-FMA vs the old 4x4's 2.0), NO barriers (one wave:
// ds ordering via lgkmcnt), 16 KB LDS, 2048 blocks x 2 chunks -> 2 waves
// per SIMD machine-wide.  fp32 facc per 64-row chunk -> fp64 dacc per
// block -> plain coalesced stores (no global atomics: r2 showed fp64
// atomics ping-pong L2 lines across XCDs).
// ---------------------------------------------------------------------------
__global__ __launch_bounds__(64) void gram_kernel(const float* __restrict__ x,
                                                  double* __restrict__ partials,
                                                  int tiles_per_block) {
    __shared__ __align__(16) float xt[64 * PP];   // 16 KB
    const int tid = threadIdx.x;   // 0..63
    const int ti = tid >> 3;       // 8 row-groups of 8
    const int tj = tid & 7;        // 8 col-groups of 8

    double dacc[8][8];
#pragma unroll
    for (int a = 0; a < 8; a++)
#pragma unroll
        for (int b = 0; b < 8; b++) dacc[a][b] = 0.0;

    xt[tid * PP + 63] = 1.0f;      // ones column (staging never writes c=63)

    const int tile0 = blockIdx.x * tiles_per_block;
    for (int t = 0; t < tiles_per_block; t++) {
        // stage 64 rows x 63 cols = 1008 float4 (single wave: no barrier;
        // compiler orders ds_write -> ds_read with lgkmcnt)
        const float4* src = (const float4*)(x + (size_t)(tile0 + t) * (64 * 63));
        for (int k = tid; k < 1008; k += 64) {
            float4 v = src[k];
            const float* ve = (const float*)&v;
            int flat = k * 4;
#pragma unroll
            for (int e = 0; e < 4; e++) {
                int f = flat + e;
                int r = f / 63;
                int c = f - r * 63;
                xt[r * PP + c] = ve[e];
            }
        }

        float facc[8][8];
#pragma unroll
        for (int a = 0; a < 8; a++)
#pragma unroll
            for (int b = 0; b < 8; b++) facc[a][b] = 0.0f;

        for (int r = 0; r < 64; r++) {
            const float* row = &xt[r * PP];
            float4 xi0 = *(const float4*)&row[ti * 8];
            float4 xi1 = *(const float4*)&row[ti * 8 + 4];
            float4 xj0 = *(const float4*)&row[tj * 8];
            float4 xj1 = *(const float4*)&row[tj * 8 + 4];
            const float xia[8] = {xi0.x, xi0.y, xi0.z, xi0.w,
                                  xi1.x, xi1.y, xi1.z, xi1.w};
            const float xja[8] = {xj0.x, xj0.y, xj0.z, xj0.w,
                                  xj1.x, xj1.y, xj1.z, xj1.w};
#pragma unroll
            for (int a = 0; a < 8; a++)
#pragma unroll
                for (int b = 0; b < 8; b++)
                    facc[a][b] = fmaf(xia[a], xja[b], facc[a][b]);
        }
#pragma unroll
        for (int a = 0; a < 8; a++)
#pragma unroll
            for (int b = 0; b < 8; b++) dacc[a][b] += (double)facc[a][b];
    }

    double* Pb = partials + (size_t)blockIdx.x * 4096;
#pragma unroll
    for (int a = 0; a < 8; a++) {
        double* dst = &Pb[(ti * 8 + a) * 64 + tj * 8];
#pragma unroll
        for (int b = 0; b < 8; b++) dst[b] = dacc[a][b];
    }
}

// ---------------------------------------------------------------------------
// K1b: fold nparts partials into G_CHUNKS copies (deterministic fp64 sums,
// block-index-ascending within each chunk — same order class as r3-r8).
// ---------------------------------------------------------------------------
__global__ __launch_bounds__(256) void reduce_kernel(const double* __restrict__ partials,
                                                     double* __restrict__ G8,
                                                     int copies_per_chunk) {
    const int chunk = blockIdx.x >> 4;             // 0..7
    const int idx   = (blockIdx.x & 15) * 256 + threadIdx.x;  // 0..4095
    const double* src = partials + (size_t)chunk * copies_per_chunk * 4096;
    double s = 0.0;
    for (int c = 0; c < copies_per_chunk; c++)
        s += src[(size_t)c * 4096 + idx];
    G8[(size_t)chunk * 4096 + idx] = s;
}

// ---------------------------------------------------------------------------
// K2: per-channel stats.  mean_d = (colsum . W_d)/M ; E[h^2]_d = W_d G W_d^T / M
// var = E[h^2] - mean^2 (fp64).  stats[d] = {mean, invstd, gamma, beta}.
// ---------------------------------------------------------------------------
__global__ __launch_bounds__(64) void stats_kernel(const double* __restrict__ G,
                                                   const float* __restrict__ W,
                                                   const float* __restrict__ gamma,
                                                   const float* __restrict__ beta,
                                                   float* __restrict__ stats) {
    const int d = blockIdx.x;    // 0..127
    const int p = threadIdx.x;   // 0..63
    __shared__ float sW[64];
    sW[p] = (p < P_DIM) ? W[d * P_DIM + p] : 0.0f;
    __syncthreads();

    double inner = 0.0;
#pragma unroll
    for (int c = 0; c < G_CHUNKS; c++) {
        const double* Gr = G + (size_t)c * (64 * 64) + p * 64;
        for (int q = 0; q < 64; q++) inner += Gr[q] * (double)sW[q];
    }

    double contrib = (double)sW[p] * inner;   // row 63 has w=0 -> no effect
    double ex2M = contrib;
#pragma unroll
    for (int off = 32; off > 0; off >>= 1) ex2M += __shfl_down(ex2M, off, 64);
    double meanM = __shfl(inner, 63, 64);     // ones-row dot W_d = colsum . W_d

    if (p == 0) {
        double mean = meanM / (double)M_ROWS;
        double ex2  = ex2M  / (double)M_ROWS;
        double var  = ex2 - mean * mean;
        float varf  = (float)var;
        float vpe   = varf + 1e-5f;                 // ref: fp32 var + fp32 eps
        float invstd = (float)(1.0 / sqrt((double)vpe));
        stats[d * 4 + 0] = (float)mean;
        stats[d * 4 + 1] = invstd;
        stats[d * 4 + 2] = gamma[d];
        stats[d * 4 + 3] = beta[d];
    }
}

// ---------------------------------------------------------------------------
// K3: on-the-fly GEMM + BN affine (ref op order) + 4-step LIF in registers.
// Exactly round-7 (best known: 80.6 us): r4 structure + nontemporal x loads
// and out stores.  r8 proved VALU *cycles*, not instruction slots, are the
// wall (pk_fma halved insts, zero time change) — leave lif alone.
// ---------------------------------------------------------------------------
#define LIF_ROWS 16
#define SW_STRIDE 132
#define SX_STRIDE 64
__global__ __launch_bounds__(256) void lif_kernel(const float* __restrict__ x,
                                                  const float* __restrict__ W,
                                                  const float* __restrict__ stats,
                                                  float* __restrict__ out) {
    __shared__ __align__(16) float sw[P_DIM * SW_STRIDE];            // 33.3 KB
    __shared__ __align__(16) float sx[T_STEPS * LIF_ROWS * SX_STRIDE]; // 16 KB
    const int tid = threadIdx.x;

    // stage W: sequential-k coalesced global reads; scatter-transpose into LDS
    for (int k = tid; k < P_DIM * D_DIM; k += 256) {
        int d = k / 63;
        int p = k - d * 63;
        sw[p * SW_STRIDE + d] = W[k];
    }

    // stage x: flat coalesced nontemporal float4 loads, scatter into stride-64
    const int r0 = blockIdx.x * LIF_ROWS;
    const int seg = tid >> 6;      // timestep
    const int lane = tid & 63;
    const v4f* src = (const v4f*)(x + ((size_t)seg * R_ROWS + r0) * P_DIM);
    for (int k = lane; k < 252; k += 64) {
        v4f v = __builtin_nontemporal_load(&src[k]);
        int flat = k * 4;
#pragma unroll
        for (int e = 0; e < 4; e++) {
            int f = flat + e;
            int r = f / 63;
            int c = f - r * 63;
            sx[(seg * LIF_ROWS + r) * SX_STRIDE + c] = v[e];
        }
    }
    __syncthreads();

    const int td = tid & 31;      // 32 channel-tiles of 4
    const int tr = tid >> 5;      // 8 row-pairs
    const int d0 = td * 4;
    const int rowa = tr * 2;

    float acc[8][4];              // [t*2+i][j]
#pragma unroll
    for (int u = 0; u < 8; u++)
#pragma unroll
        for (int j = 0; j < 4; j++) acc[u][j] = 0.0f;

    // main loop: 15 p-quads (p = 0..59)
    for (int pq = 0; pq < 15; pq++) {
        const int p = pq * 4;
        float4 w0 = *(const float4*)&sw[(p + 0) * SW_STRIDE + d0];
        float4 w1 = *(const float4*)&sw[(p + 1) * SW_STRIDE + d0];
        float4 w2 = *(const float4*)&sw[(p + 2) * SW_STRIDE + d0];
        float4 w3 = *(const float4*)&sw[(p + 3) * SW_STRIDE + d0];
#pragma unroll
        for (int t = 0; t < T_STEPS; t++)
#pragma unroll
            for (int i = 0; i < 2; i++) {
                float4 xv = *(const float4*)&sx[(t * LIF_ROWS + rowa + i) * SX_STRIDE + p];
                float* a = acc[t * 2 + i];
                a[0] = fmaf(xv.x, w0.x, a[0]);
                a[1] = fmaf(xv.x, w0.y, a[1]);
                a[2] = fmaf(xv.x, w0.z, a[2]);
                a[3] = fmaf(xv.x, w0.w, a[3]);
                a[0] = fmaf(xv.y, w1.x, a[0]);
                a[1] = fmaf(xv.y, w1.y, a[1]);
                a[2] = fmaf(xv.y, w1.z, a[2]);
                a[3] = fmaf(xv.y, w1.w, a[3]);
                a[0] = fmaf(xv.z, w2.x, a[0]);
                a[1] = fmaf(xv.z, w2.y, a[1]);
                a[2] = fmaf(xv.z, w2.z, a[2]);
                a[3] = fmaf(xv.z, w2.w, a[3]);
                a[0] = fmaf(xv.w, w3.x, a[0]);
                a[1] = fmaf(xv.w, w3.y, a[1]);
                a[2] = fmaf(xv.w, w3.z, a[2]);
                a[3] = fmaf(xv.w, w3.w, a[3]);
            }
    }
    // tail: p = 60, 61, 62 (same ascending order)
#pragma unroll
    for (int p = 60; p < 63; p++) {
        float4 w4 = *(const float4*)&sw[p * SW_STRIDE + d0];
#pragma unroll
        for (int t = 0; t < T_STEPS; t++)
#pragma unroll
            for (int i = 0; i < 2; i++) {
                float xv = sx[(t * LIF_ROWS + rowa + i) * SX_STRIDE + p];
                float* a = acc[t * 2 + i];
                a[0] = fmaf(xv, w4.x, a[0]);
                a[1] = fmaf(xv, w4.y, a[1]);
                a[2] = fmaf(xv, w4.z, a[2]);
                a[3] = fmaf(xv, w4.w, a[3]);
            }
    }

    // epilogue: BN affine (ref op order) + LIF scan; nontemporal b128 stores
#pragma unroll
    for (int i = 0; i < 2; i++) {
        const int row = r0 + rowa + i;
        float sval[T_STEPS][4];
#pragma unroll
        for (int j = 0; j < 4; j++) {
            float4 st = ((const float4*)stats)[d0 + j];  // mean, invstd, gamma, beta
            float v = 0.0f;
#pragma unroll
            for (int t = 0; t < T_STEPS; t++) {
                float hn = (acc[t * 2 + i][j] - st.x) * st.y;
                hn = hn * st.z;
                hn = hn + st.w;
                v = v + (hn - v) * 0.5f;       // == v + (x-v)/2, exact
                float s = (v >= 1.0f) ? 1.0f : 0.0f;  // (v-1>=0) sign-exact
                sval[t][j] = s;
                if (s != 0.0f) v = 0.0f;       // hard reset
            }
        }
#pragma unroll
        for (int t = 0; t < T_STEPS; t++) {
            v4f o = {sval[t][0], sval[t][1], sval[t][2], sval[t][3]};
            __builtin_nontemporal_store(
                o, (v4f*)&out[((size_t)t * R_ROWS + row) * D_DIM + d0]);
        }
    }
}

// ---------------------------------------------------------------------------
extern "C" void kernel_launch(void* const* d_in, const int* in_sizes, int n_in,
                              void* d_out, int out_size, void* d_ws, size_t ws_size,
                              hipStream_t stream) {
    const float* x     = (const float*)d_in[0];
    const float* W     = (const float*)d_in[1];
    const float* gamma = (const float*)d_in[2];
    const float* beta  = (const float*)d_in[3];
    float* out = (float*)d_out;

    // pick partial count by available workspace (power of 2, 256..2048)
    const size_t fixed = (size_t)G_CHUNKS * 4096 * 8 + 4096;  // G8 + stats + pad
    int nparts = 2048;
    while (nparts > 256 && (size_t)nparts * 4096 * 8 + fixed > ws_size) nparts >>= 1;
    const int tiles_per_block = TILES_TOTAL / nparts;

    double* partials = (double*)d_ws;
    double* G8       = (double*)((char*)d_ws + (size_t)nparts * 4096 * 8);
    float*  stats    = (float*)((char*)G8 + (size_t)G_CHUNKS * 4096 * 8);

    gram_kernel<<<nparts, 64, 0, stream>>>(x, partials, tiles_per_block);
    reduce_kernel<<<G_CHUNKS * 16, 256, 0, stream>>>(partials, G8, nparts / G_CHUNKS);
    stats_kernel<<<D_DIM, 64, 0, stream>>>(G8, W, gamma, beta, stats);
    lif_kernel<<<R_ROWS / LIF_ROWS, 256, 0, stream>>>(x, W, stats, out);
}

// Round 10
// 285.385 us; speedup vs baseline: 1.2572x; 1.2572x over previous
//
#include <hip/hip_runtime.h>
#include <math.h>

// Problem constants (from reference setup): T=4, B=64, N=1024, P=63, D=128
#define T_STEPS 4
#define R_ROWS  65536              // B*N rows per timestep
#define M_ROWS  262144             // T*B*N total rows
#define P_DIM   63
#define D_DIM   128
#define PP      64                 // padded P (col 63 = virtual ones column in K1)

#define TILES_TOTAL (M_ROWS / 64)  // 4096 tiles of 64 rows
#define G_CHUNKS 8                 // reduce output copies consumed by stats

typedef float v4f __attribute__((ext_vector_type(4)));

// ---------------------------------------------------------------------------
// K1: per-block partial Gram  P_b = xa_b^T xa_b  (xa = x + ones column).
// r8 config restored (r9's single-wave 8x8 variant regressed: 128 fp64 VGPR
// accumulator -> ~1 wave/SIMD, latency exposed).  256 threads, 4x4 tiles,
// double-buffered LDS staging, fp64 per-block, plain coalesced stores.
// ---------------------------------------------------------------------------
__global__ __launch_bounds__(256) void gram_kernel(const float* __restrict__ x,
                                                   double* __restrict__ partials,
                                                   int tiles_per_block) {
    __shared__ __align__(16) float xt[2][64 * PP];
    const int tid = threadIdx.x;
    const int tj = tid & 15;       // 16 col-tiles of 4
    const int ti = tid >> 4;       // 16 row-tiles of 4

    double dacc[4][4];
#pragma unroll
    for (int a = 0; a < 4; a++)
#pragma unroll
        for (int b = 0; b < 4; b++) dacc[a][b] = 0.0;

    if (tid < 64) {                // ones column in both buffers (never overwritten)
        xt[0][tid * PP + 63] = 1.0f;
        xt[1][tid * PP + 63] = 1.0f;
    }

    const int tile0 = blockIdx.x * tiles_per_block;
    float4 reg[4];

    {
        const float4* src = (const float4*)(x + (size_t)tile0 * (64 * 63));
#pragma unroll
        for (int it = 0; it < 4; it++) {
            int k = tid + it * 256;
            reg[it] = (k < 1008) ? src[k] : make_float4(0.f, 0.f, 0.f, 0.f);
        }
    }
#pragma unroll
    for (int it = 0; it < 4; it++) {
        int k = tid + it * 256;
        if (k < 1008) {
            const float* ve = (const float*)&reg[it];
            int flat = k * 4;
#pragma unroll
            for (int e = 0; e < 4; e++) {
                int f = flat + e;
                int r = f / 63;
                int c = f - r * 63;
                xt[0][r * PP + c] = ve[e];
            }
        }
    }
    __syncthreads();

    for (int t = 0; t < tiles_per_block; t++) {
        const int cur = t & 1;
        if (t + 1 < tiles_per_block) {
            const float4* src = (const float4*)(x + (size_t)(tile0 + t + 1) * (64 * 63));
#pragma unroll
            for (int it = 0; it < 4; it++) {
                int k = tid + it * 256;
                reg[it] = (k < 1008) ? src[k] : make_float4(0.f, 0.f, 0.f, 0.f);
            }
        }

        float facc[4][4];
#pragma unroll
        for (int a = 0; a < 4; a++)
#pragma unroll
            for (int b = 0; b < 4; b++) facc[a][b] = 0.0f;

        const float* buf = xt[cur];
        for (int r = 0; r < 64; r++) {
            float4 xi = *(const float4*)&buf[r * PP + ti * 4];
            float4 xj = *(const float4*)&buf[r * PP + tj * 4];
            const float* xia = (const float*)&xi;
            const float* xja = (const float*)&xj;
#pragma unroll
            for (int a = 0; a < 4; a++)
#pragma unroll
                for (int b = 0; b < 4; b++)
                    facc[a][b] = fmaf(xia[a], xja[b], facc[a][b]);
        }
#pragma unroll
        for (int a = 0; a < 4; a++)
#pragma unroll
            for (int b = 0; b < 4; b++) dacc[a][b] += (double)facc[a][b];

        __syncthreads();
        if (t + 1 < tiles_per_block) {
            float* nbuf = xt[1 - cur];
#pragma unroll
            for (int it = 0; it < 4; it++) {
                int k = tid + it * 256;
                if (k < 1008) {
                    const float* ve = (const float*)&reg[it];
                    int flat = k * 4;
#pragma unroll
                    for (int e = 0; e < 4; e++) {
                        int f = flat + e;
                        int r = f / 63;
                        int c = f - r * 63;
                        nbuf[r * PP + c] = ve[e];
                    }
                }
            }
            __syncthreads();
        }
    }

    double* Pb = partials + (size_t)blockIdx.x * 4096;
#pragma unroll
    for (int a = 0; a < 4; a++)
#pragma unroll
        for (int b = 0; b < 4; b++)
            Pb[(ti * 4 + a) * 64 + (tj * 4 + b)] = dacc[a][b];
}

// ---------------------------------------------------------------------------
// K1b: fold nparts partials into G_CHUNKS copies (deterministic fp64 sums).
// Blocks >= 128 instead build Wt[p*128+d] = W[d*63+p] (needed by lif; folded
// here to avoid an extra launch — runs in dispatch-parallel with the folds).
// ---------------------------------------------------------------------------
__global__ __launch_bounds__(256) void reduce_kernel(const double* __restrict__ partials,
                                                     double* __restrict__ G8,
                                                     const float* __restrict__ W,
                                                     float* __restrict__ Wt,
                                                     int copies_per_chunk) {
    if (blockIdx.x >= G_CHUNKS * 16) {
        int widx = (blockIdx.x - G_CHUNKS * 16) * 256 + threadIdx.x;
        for (int j = widx; j < P_DIM * D_DIM; j += 8 * 256) {
            int p = j >> 7;
            int d = j & 127;
            Wt[j] = W[d * P_DIM + p];
        }
        return;
    }
    const int chunk = blockIdx.x >> 4;             // 0..7
    const int idx   = (blockIdx.x & 15) * 256 + threadIdx.x;  // 0..4095
    const double* src = partials + (size_t)chunk * copies_per_chunk * 4096;
    double s = 0.0;
    for (int c = 0; c < copies_per_chunk; c++)
        s += src[(size_t)c * 4096 + idx];
    G8[(size_t)chunk * 4096 + idx] = s;
}

// ---------------------------------------------------------------------------
// K2: per-channel stats.  mean_d = (colsum . W_d)/M ; E[h^2]_d = W_d G W_d^T / M
// var = E[h^2] - mean^2 (fp64).  stats[d] = {mean, invstd, gamma, beta}.
// ---------------------------------------------------------------------------
__global__ __launch_bounds__(64) void stats_kernel(const double* __restrict__ G,
                                                   const float* __restrict__ W,
                                                   const float* __restrict__ gamma,
                                                   const float* __restrict__ beta,
                                                   float* __restrict__ stats) {
    const int d = blockIdx.x;    // 0..127
    const int p = threadIdx.x;   // 0..63
    __shared__ float sW[64];
    sW[p] = (p < P_DIM) ? W[d * P_DIM + p] : 0.0f;
    __syncthreads();

    double inner = 0.0;
#pragma unroll
    for (int c = 0; c < G_CHUNKS; c++) {
        const double* Gr = G + (size_t)c * (64 * 64) + p * 64;
        for (int q = 0; q < 64; q++) inner += Gr[q] * (double)sW[q];
    }

    double contrib = (double)sW[p] * inner;   // row 63 has w=0 -> no effect
    double ex2M = contrib;
#pragma unroll
    for (int off = 32; off > 0; off >>= 1) ex2M += __shfl_down(ex2M, off, 64);
    double meanM = __shfl(inner, 63, 64);     // ones-row dot W_d = colsum . W_d

    if (p == 0) {
        double mean = meanM / (double)M_ROWS;
        double ex2  = ex2M  / (double)M_ROWS;
        double var  = ex2 - mean * mean;
        float varf  = (float)var;
        float vpe   = varf + 1e-5f;                 // ref: fp32 var + fp32 eps
        float invstd = (float)(1.0 / sqrt((double)vpe));
        stats[d * 4 + 0] = (float)mean;
        stats[d * 4 + 1] = invstd;
        stats[d * 4 + 2] = gamma[d];
        stats[d * 4 + 3] = beta[d];
    }
}

// ---------------------------------------------------------------------------
// K3: on-the-fly GEMM + BN affine (ref op order) + 4-step LIF in registers.
// Round-10: r7 structure with the ~30us of non-FMA VALU attacked (r9 cycle
// accounting: VALUBusy*dur=57us, FMA=27us, rest = W-transpose-with-div63
// ~350 inst + rolled-loop addressing ~300 + staging + epilogue):
//   (a) W staged from precomputed Wt via flat float4 copy (stride 128 is
//       conflict-free for b128: each 8-lane phase covers all 32 banks);
//   (b) pq loop FULLY UNROLLED: sx addr = one VGPR base + imm offset
//       (t*4096+i*256+p*16 <= 13.5KB), sw addr = base(d0*4) + imm (p*512)
//       -> main-loop address VALU ~0.
// fmaf chains identical values, ascending-p -> bitwise-identical accs.
// ---------------------------------------------------------------------------
#define LIF_ROWS 16
#define SX_STRIDE 64
__global__ __launch_bounds__(256) void lif_kernel(const float* __restrict__ x,
                                                  const float* __restrict__ Wt,
                                                  const float* __restrict__ stats,
                                                  float* __restrict__ out) {
    __shared__ __align__(16) float sw[P_DIM * D_DIM];                // 32256 B
    __shared__ __align__(16) float sx[T_STEPS * LIF_ROWS * SX_STRIDE]; // 16384 B
    const int tid = threadIdx.x;

    // stage Wt: flat float4 copy (2016 float4), conflict-free, no div
    {
        const float4* wt4 = (const float4*)Wt;
        float4* sw4 = (float4*)sw;
#pragma unroll
        for (int i = 0; i < 8; i++) {
            int k = tid + i * 256;
            if (k < 2016) sw4[k] = wt4[k];
        }
    }

    // stage x: flat coalesced nontemporal float4 loads, scatter into stride-64
    const int r0 = blockIdx.x * LIF_ROWS;
    const int seg = tid >> 6;      // timestep
    const int lane = tid & 63;
    const v4f* src = (const v4f*)(x + ((size_t)seg * R_ROWS + r0) * P_DIM);
#pragma unroll
    for (int kk = 0; kk < 4; kk++) {
        int k = lane + kk * 64;    // < 256; 252 valid
        v4f v;
        if (k < 252) v = __builtin_nontemporal_load(&src[k]);
        if (k < 252) {
            int flat = k * 4;
#pragma unroll
            for (int e = 0; e < 4; e++) {
                int f = flat + e;
                int r = f / 63;
                int c = f - r * 63;
                sx[(seg * LIF_ROWS + r) * SX_STRIDE + c] = v[e];
            }
        }
    }
    __syncthreads();

    const int td = tid & 31;      // 32 channel-tiles of 4
    const int tr = tid >> 5;      // 8 row-pairs
    const int d0 = td * 4;
    const int rowa = tr * 2;

    float acc[8][4];              // [t*2+i][j]
#pragma unroll
    for (int u = 0; u < 8; u++)
#pragma unroll
        for (int j = 0; j < 4; j++) acc[u][j] = 0.0f;

    // main loop: 15 p-quads, FULLY UNROLLED (imm ds offsets)
#pragma unroll
    for (int pq = 0; pq < 15; pq++) {
        const int p = pq * 4;
        float4 w0 = *(const float4*)&sw[(p + 0) * D_DIM + d0];
        float4 w1 = *(const float4*)&sw[(p + 1) * D_DIM + d0];
        float4 w2 = *(const float4*)&sw[(p + 2) * D_DIM + d0];
        float4 w3 = *(const float4*)&sw[(p + 3) * D_DIM + d0];
#pragma unroll
        for (int t = 0; t < T_STEPS; t++)
#pragma unroll
            for (int i = 0; i < 2; i++) {
                float4 xv = *(const float4*)&sx[(t * LIF_ROWS + rowa + i) * SX_STRIDE + p];
                float* a = acc[t * 2 + i];
                a[0] = fmaf(xv.x, w0.x, a[0]);
                a[1] = fmaf(xv.x, w0.y, a[1]);
                a[2] = fmaf(xv.x, w0.z, a[2]);
                a[3] = fmaf(xv.x, w0.w, a[3]);
                a[0] = fmaf(xv.y, w1.x, a[0]);
                a[1] = fmaf(xv.y, w1.y, a[1]);
                a[2] = fmaf(xv.y, w1.z, a[2]);
                a[3] = fmaf(xv.y, w1.w, a[3]);
                a[0] = fmaf(xv.z, w2.x, a[0]);
                a[1] = fmaf(xv.z, w2.y, a[1]);
                a[2] = fmaf(xv.z, w2.z, a[2]);
                a[3] = fmaf(xv.z, w2.w, a[3]);
                a[0] = fmaf(xv.w, w3.x, a[0]);
                a[1] = fmaf(xv.w, w3.y, a[1]);
                a[2] = fmaf(xv.w, w3.z, a[2]);
                a[3] = fmaf(xv.w, w3.w, a[3]);
            }
    }
    // tail: p = 60, 61, 62 (same ascending order)
#pragma unroll
    for (int p = 60; p < 63; p++) {
        float4 w4 = *(const float4*)&sw[p * D_DIM + d0];
#pragma unroll
        for (int t = 0; t < T_STEPS; t++)
#pragma unroll
            for (int i = 0; i < 2; i++) {
                float xv = sx[(t * LIF_ROWS + rowa + i) * SX_STRIDE + p];
                float* a = acc[t * 2 + i];
                a[0] = fmaf(xv, w4.x, a[0]);
                a[1] = fmaf(xv, w4.y, a[1]);
                a[2] = fmaf(xv, w4.z, a[2]);
                a[3] = fmaf(xv, w4.w, a[3]);
            }
    }

    // epilogue: BN affine (ref op order) + LIF scan; nontemporal b128 stores
#pragma unroll
    for (int i = 0; i < 2; i++) {
        const int row = r0 + rowa + i;
        float sval[T_STEPS][4];
#pragma unroll
        for (int j = 0; j < 4; j++) {
            float4 st = ((const float4*)stats)[d0 + j];  // mean, invstd, gamma, beta
            float v = 0.0f;
#pragma unroll
            for (int t = 0; t < T_STEPS; t++) {
                float hn = (acc[t * 2 + i][j] - st.x) * st.y;
                hn = hn * st.z;
                hn = hn + st.w;
                v = v + (hn - v) * 0.5f;       // == v + (x-v)/2, exact
                float s = (v >= 1.0f) ? 1.0f : 0.0f;  // (v-1>=0) sign-exact
                sval[t][j] = s;
                if (s != 0.0f) v = 0.0f;       // hard reset
            }
        }
#pragma unroll
        for (int t = 0; t < T_STEPS; t++) {
            v4f o = {sval[t][0], sval[t][1], sval[t][2], sval[t][3]};
            __builtin_nontemporal_store(
                o, (v4f*)&out[((size_t)t * R_ROWS + row) * D_DIM + d0]);
        }
    }
}

// ---------------------------------------------------------------------------
extern "C" void kernel_launch(void* const* d_in, const int* in_sizes, int n_in,
                              void* d_out, int out_size, void* d_ws, size_t ws_size,
                              hipStream_t stream) {
    const float* x     = (const float*)d_in[0];
    const float* W     = (const float*)d_in[1];
    const float* gamma = (const float*)d_in[2];
    const float* beta  = (const float*)d_in[3];
    float* out = (float*)d_out;

    // pick partial count by available workspace (power of 2, 64..512)
    const size_t fixed = (size_t)G_CHUNKS * 4096 * 8 + 2048 + 32768 + 4096;
    int nparts = 512;
    while (nparts > 64 && (size_t)nparts * 4096 * 8 + fixed > ws_size) nparts >>= 1;
    const int tiles_per_block = TILES_TOTAL / nparts;

    double* partials = (double*)d_ws;
    double* G8       = (double*)((char*)d_ws + (size_t)nparts * 4096 * 8);
    float*  stats    = (float*)((char*)G8 + (size_t)G_CHUNKS * 4096 * 8);
    float*  Wt       = (float*)((char*)stats + 2048);

    gram_kernel<<<nparts, 256, 0, stream>>>(x, partials, tiles_per_block);
    reduce_kernel<<<G_CHUNKS * 16 + 8, 256, 0, stream>>>(partials, G8, W, Wt,
                                                         nparts / G_CHUNKS);
    stats_kernel<<<D_DIM, 64, 0, stream>>>(G8, W, gamma, beta, stats);
    lif_kernel<<<R_ROWS / LIF_ROWS, 256, 0, stream>>>(x, Wt, stats, out);
}